// Round 18
// baseline (141.819 us; speedup 1.0000x reference)
//
#include <hip/hip_runtime.h>
#include <hip/hip_bf16.h>
#include <stdint.h>

#define IN_F 2048
#define OUT_F 128
#define KD 32
#define NR 256
#define OC 2176          // IN_F + OUT_F
#define OD 4096          // OUT_F * KD (T row stride)
#define THRESH 32.0f
#define KSN 16           // k-slices of 128
#define OPN (1024 * 256) // elems per Pp partial

// ---- instrumentation: rotation-repeat so each dispatch exceeds the ~40us
// ---- fill floor and appears in rocprof top-5 with its counters. Each rep
// ---- covers the full problem once with bit-identical writes.
#define REP_K1 8
#define REP_K2 8

typedef __bf16 bf16x8 __attribute__((ext_vector_type(8)));
typedef __bf16 bf16x4 __attribute__((ext_vector_type(4)));
typedef float  f32x4  __attribute__((ext_vector_type(4)));
typedef uint16_t u16x8 __attribute__((ext_vector_type(8)));

// ---------------------------------------------------------------------------
// K1 (instrumented R17): fused tproj + sgemm + x-copy.
// ---------------------------------------------------------------------------
__global__ __launch_bounds__(256, 2) void fused_kernel(const float* __restrict__ x,
                                                       const float* __restrict__ Tm,
                                                       float* __restrict__ out,
                                                       __bf16* __restrict__ Pp) {
    __shared__ __bf16 Bs[32][136];
    __shared__ __bf16 As[2][4][256][8];

    const int tid  = threadIdx.x;
    const int lane = tid & 63;
    const int wid  = tid >> 6;
    const int fr   = lane & 15, fg = lane >> 4;

    #pragma unroll 1
    for (int r = 0; r < REP_K1; ++r) {
        __syncthreads();                 // LDS reuse guard across reps
        const int bid = (blockIdx.x + r * 64) & 511;
        const int ks  = bid & 15;
        const int fo  = bid >> 4;
        const int k0  = ks * 128;

        // x -> out copy
        {
            const int row = bid >> 1;
            const int off = (bid & 1) * 1024 + tid * 4;
            float4 v = *reinterpret_cast<const float4*>(&x[row * IN_F + off]);
            *reinterpret_cast<float4*>(&out[row * OC + off]) = v;
        }

        // x chunk-0 prefetch
        float4 xs[8];
        const int kslot = tid & 7;
        const int nrow8 = tid >> 3;
        #pragma unroll
        for (int p = 0; p < 8; ++p)
            xs[p] = *reinterpret_cast<const float4*>(&x[(p * 32 + nrow8) * IN_F + k0 + kslot * 4]);

        // tproj: 2 (k,f) pairs per thread
        #pragma unroll 1
        for (int rr = 0; rr < 2; ++rr) {
            const int idx = rr * 256 + tid;
            const int fl  = idx & 3;
            const int kl  = idx >> 2;
            const float* src = Tm + (size_t)(k0 + kl) * OD + (fo * 4 + fl) * KD;

            float v[32];
            #pragma unroll
            for (int q = 0; q < 8; ++q) {
                f32x4 w = *reinterpret_cast<const f32x4*>(src + q * 4);
                v[q * 4]     = w[0];
                v[q * 4 + 1] = w[1];
                v[q * 4 + 2] = w[2];
                v[q * 4 + 3] = w[3];
            }

            float s1[16], d1[16];
            #pragma unroll
            for (int e = 0; e < 16; ++e) { s1[e] = v[2*e] + v[2*e+1]; d1[e] = v[2*e] - v[2*e+1]; }
            float s2[8], d2[8];
            #pragma unroll
            for (int e = 0; e < 8; ++e)  { s2[e] = s1[2*e] + s1[2*e+1]; d2[e] = s1[2*e] - s1[2*e+1]; }
            float s3[4], d3[4];
            #pragma unroll
            for (int e = 0; e < 4; ++e)  { s3[e] = s2[2*e] + s2[2*e+1]; d3[e] = s2[2*e] - s2[2*e+1]; }
            float s4[2], d4[2];
            #pragma unroll
            for (int e = 0; e < 2; ++e)  { s4[e] = s3[2*e] + s3[2*e+1]; d4[e] = s3[2*e] - s3[2*e+1]; }
            const float s5 = s4[0] + s4[1];
            const float d5 = s4[0] - s4[1];

            float pr[8];
            pr[0] = s5;
            { float s = 0.f;
              #pragma unroll
              for (int e = 0; e < 16; ++e) s += d1[e];
              pr[1] = s; }
            { float s = 0.f;
              #pragma unroll
              for (int e = 0; e < 8; ++e) s += d2[e];
              pr[2] = s; }
            pr[3] = (d3[0] + d3[1]) + (d3[2] + d3[3]);
            pr[4] = d4[0] + d4[1];
            pr[5] = d5;
            { float s = 0.f;
              #pragma unroll
              for (int g = 0; g < 8; ++g) s += d1[2*g] - d1[2*g+1];
              pr[6] = s; }
            pr[7] = s3[0] - s3[1] - s3[2] + s3[3];

            #pragma unroll
            for (int p = 0; p < 8; ++p)
                Bs[fl * 8 + p][kl] = (__bf16)pr[p];
        }

        #pragma unroll
        for (int p = 0; p < 8; ++p) {
            bf16x4 b = { (__bf16)xs[p].x, (__bf16)xs[p].y, (__bf16)xs[p].z, (__bf16)xs[p].w };
            *reinterpret_cast<bf16x4*>(&As[0][kslot >> 1][p * 32 + nrow8][(kslot & 1) * 4]) = b;
        }
        __syncthreads();

        f32x4 acc[4][2] = {};

        #pragma unroll 1
        for (int c = 0; c < 4; ++c) {
            const int buf = c & 1;
            if (c < 3) {
                #pragma unroll
                for (int p = 0; p < 8; ++p)
                    xs[p] = *reinterpret_cast<const float4*>(
                        &x[(p * 32 + nrow8) * IN_F + k0 + (c + 1) * 32 + kslot * 4]);
            }

            bf16x8 bfrag[2];
            #pragma unroll
            for (int oi = 0; oi < 2; ++oi)
                bfrag[oi] = *reinterpret_cast<const bf16x8*>(&Bs[oi * 16 + fr][c * 32 + fg * 8]);
            #pragma unroll
            for (int mi = 0; mi < 4; ++mi) {
                bf16x8 af = *reinterpret_cast<const bf16x8*>(&As[buf][fg][wid * 64 + mi * 16 + fr][0]);
                acc[mi][0] = __builtin_amdgcn_mfma_f32_16x16x32_bf16(af, bfrag[0], acc[mi][0], 0, 0, 0);
                acc[mi][1] = __builtin_amdgcn_mfma_f32_16x16x32_bf16(af, bfrag[1], acc[mi][1], 0, 0, 0);
            }

            if (c < 3) {
                __syncthreads();
                #pragma unroll
                for (int p = 0; p < 8; ++p) {
                    bf16x4 b = { (__bf16)xs[p].x, (__bf16)xs[p].y, (__bf16)xs[p].z, (__bf16)xs[p].w };
                    *reinterpret_cast<bf16x4*>(&As[buf ^ 1][kslot >> 1][p * 32 + nrow8][(kslot & 1) * 4]) = b;
                }
                __syncthreads();
            }
        }

        __bf16* dst = Pp + (size_t)ks * OPN;
        #pragma unroll
        for (int mi = 0; mi < 4; ++mi) {
            #pragma unroll
            for (int oi = 0; oi < 2; ++oi) {
                const int op = fo * 32 + oi * 16 + fr;
                const int nb = wid * 64 + mi * 16 + fg * 4;
                bf16x4 v = { (__bf16)acc[mi][oi][0], (__bf16)acc[mi][oi][1],
                             (__bf16)acc[mi][oi][2], (__bf16)acc[mi][oi][3] };
                *reinterpret_cast<bf16x4*>(&dst[(size_t)op * NR + nb]) = v;
            }
        }
    }
}

// ---------------------------------------------------------------------------
// K2 (instrumented R17): screen.
// ---------------------------------------------------------------------------
__global__ __launch_bounds__(256, 2) void screen_kernel(const __bf16* __restrict__ Pp,
                                                        const float* __restrict__ x,
                                                        const float* __restrict__ Tm,
                                                        float* __restrict__ out) {
    __shared__ float P8s[256][8];
    __shared__ float part[4][64];

    const int jq   = blockIdx.y;
    const int tid  = threadIdx.x;
    const int lane = tid & 63;
    const int wid  = tid >> 6;

    #pragma unroll 1
    for (int r = 0; r < REP_K2; ++r) {
        const int f = (blockIdx.x + r * 16) & 127;
        const int j = jq * 64 + lane;

        {
            const int p  = tid >> 5;
            const int n0 = (tid & 31) * 8;
            const uint16_t* base = reinterpret_cast<const uint16_t*>(Pp)
                                 + (size_t)(f * 8 + p) * NR + n0;
            float a[8] = {};
            #pragma unroll
            for (int ks = 0; ks < KSN; ++ks) {
                u16x8 v = *reinterpret_cast<const u16x8*>(base + (size_t)ks * OPN);
                #pragma unroll
                for (int e = 0; e < 8; ++e)
                    a[e] += __builtin_bit_cast(float, (uint32_t)v[e] << 16);
            }
            #pragma unroll
            for (int e = 0; e < 8; ++e)
                P8s[n0 + e][p] = a[e];
        }
        __syncthreads();

        const f32x4 qj0 = *reinterpret_cast<const f32x4*>(&P8s[j][0]);
        const f32x4 qj1 = *reinterpret_cast<const f32x4*>(&P8s[j][4]);

        float acc = 0.f;
        const int i0 = wid * 64;
        #pragma unroll 2
        for (int ii = 0; ii < 64; ++ii) {
            const int i = i0 + ii;
            f32x4 r0 = *reinterpret_cast<const f32x4*>(&P8s[i][0]);
            f32x4 r1 = *reinterpret_cast<const f32x4*>(&P8s[i][4]);
            f32x4 d0 = r0 - qj0;
            f32x4 d1 = r1 - qj1;
            float m0 = fmaxf(fmaxf(fabsf(d0[0]), fabsf(d0[1])), fabsf(d0[2]));
            float m1 = fmaxf(fmaxf(fabsf(d0[3]), fabsf(d1[0])), fabsf(d1[1]));
            float m2 = fmaxf(fabsf(d1[2]), fabsf(d1[3]));
            const float mx = fmaxf(fmaxf(m0, m1), m2);

            const bool ok = (mx < THRESH) && (i != j);
            if (__builtin_expect(__any(ok), 0)) {
                if (ok) {
                    f32x4 ad[8] = {};
                    const float* xi = x + (size_t)i * IN_F;
                    const float* xj = x + (size_t)j * IN_F;
                    for (int k = 0; k < IN_F; ++k) {
                        const float dk = xi[k] - xj[k];
                        const float* tr = Tm + (size_t)k * OD + f * KD;
                        #pragma unroll
                        for (int q = 0; q < 8; ++q) {
                            f32x4 tv = *reinterpret_cast<const f32x4*>(tr + q * 4);
                            ad[q] += dk * tv;
                        }
                    }
                    float norm = 0.f;
                    #pragma unroll
                    for (int q = 0; q < 8; ++q)
                        norm += fabsf(ad[q][0]) + fabsf(ad[q][1])
                              + fabsf(ad[q][2]) + fabsf(ad[q][3]);
                    acc += __expf(-norm);
                }
            }
        }

        if (wid == jq) acc += 1.0f;

        part[wid][lane] = acc;
        __syncthreads();
        if (tid < 64) {
            float s = part[0][tid] + part[1][tid] + part[2][tid] + part[3][tid];
            out[(jq * 64 + tid) * OC + IN_F + f] = s;
        }
        __syncthreads();                 // next rep re-stages P8s
    }
}

extern "C" void kernel_launch(void* const* d_in, const int* in_sizes, int n_in,
                              void* d_out, int out_size, void* d_ws, size_t ws_size,
                              hipStream_t stream) {
    const float* x  = (const float*)d_in[0];   // [256, 2048] f32
    const float* Tm = (const float*)d_in[1];   // [2048, 4096] f32
    float* out = (float*)d_out;                // [256, 2176] f32

    __bf16* Pp = (__bf16*)d_ws;                // 8 MB: 16 bf16 o'-major partials

    fused_kernel<<<dim3(512), 256, 0, stream>>>(x, Tm, out, Pp);
    screen_kernel<<<dim3(128, 4), 256, 0, stream>>>(Pp, x, Tm, out);
}